// Round 12
// baseline (89861.102 us; speedup 1.0000x reference)
//
#include <hip/hip_runtime.h>

// B=64, T=256, H=1024, L=6. Cell: h = tanh((prev + h_old) @ W^T + b1 + b2).
// v12: MALL-traffic-minimized dataflow. r6-r11 established: the ONLY working
// cross-block transport is agent-scope atomics via the MALL (~1.35 TB/s for
// our access pattern); v8 gathered 16 MB/cell-gen -> 11.9us/cell BW wall.
// Changes vs v8 (all sync primitives identical & proven):
//  1. LDS RING: the P-vector gathered at (t,l) IS the h_old of (t+1,l-1).
//     ring[6][4][1024] (96 KB) caches it locally -> H never crosses memory.
//     All ring accesses are same-thread (index [l][b][tid]) -> hazard-free.
//  2. 16 groups x 16 blocks x 64 j-rows (W = 256 VGPR/thread, 1 wave/SIMD),
//     4 batches/group -> per-cell-gen gather = 256 x 16 KB = 4 MB (4x less),
//     sync degree 16 (was 32).
// Tags: y stored as y+o(t), o(t)=8+8*((t>>1)&1); h0 layer-5 published +64.
// Bounded spins -> failures visible. hstate scrubbed per launch (tag ABA).

#define BB 64
#define TT 256
#define HH 1024
#define LL 6
#define NGRP 16   // groups (4 batches each)
#define GBAT 4    // batches per group
#define NQJ 16    // j-slice blocks per group
#define RJ 64     // j rows per block
#define NTH 256
#define MAXIT (1 << 16)

#define HSTATE_BYTES (2ull * BB * LL * HH * 4)   // [parity][b][l][k], 3 MB

typedef float f32x4 __attribute__((ext_vector_type(4)));

static __device__ __forceinline__ float2 aload2(const float* p) {
    unsigned long long u = __hip_atomic_load((const unsigned long long*)p,
        __ATOMIC_RELAXED, __HIP_MEMORY_SCOPE_AGENT);
    union { unsigned long long u; float2 f; } c; c.u = u; return c.f;
}
static __device__ __forceinline__ void astore1(float* p, float v) {
    __hip_atomic_store(p, v, __ATOMIC_RELAXED, __HIP_MEMORY_SCOPE_AGENT);
}

// gather 4 batches' 16B at base + r*6144 floats (LL*HH = 6144), agent scope
static __device__ __forceinline__ void gather4(const float* base, f32x4* o) {
#pragma unroll
    for (int r = 0; r < GBAT; ++r) {
        const float* p = base + (size_t)r * (LL * HH);
        float2 a = aload2(p), b = aload2(p + 2);
        o[r] = (f32x4){a.x, a.y, b.x, b.y};
    }
}
static __device__ __forceinline__ bool valid4(const f32x4* v, float tag, float tol) {
    bool ok = true;
#pragma unroll
    for (int r = 0; r < GBAT; ++r)
        ok = ok && fabsf(v[r].x - tag) <= tol && fabsf(v[r].y - tag) <= tol
                && fabsf(v[r].z - tag) <= tol && fabsf(v[r].w - tag) <= tol;
    return ok;
}

__global__ void __launch_bounds__(NTH, 1)
rnn_kernel(const float* __restrict__ h0,
           const float* __restrict__ Whh,
           const float* __restrict__ bias_ih,
           const float* __restrict__ bias_bh,
           const float* __restrict__ w_out,
           const float* __restrict__ b_out,
           float* hstate,
           float* __restrict__ d_out)
{
    __shared__ f32x4 ring[LL][GBAT][256];    // 96 KB: RAW h values, per-thread slots
    __shared__ f32x4 s4[GBAT][256];          // 16 KB: s = prev + h_old
    __shared__ float pred[4][RJ][GBAT + 1];  //  5 KB: per-kslice partials
    __shared__ float outred[4];

    const int tid = threadIdx.x;
    const int g   = blockIdx.x & (NGRP - 1);     // group (4 batches)
    const int q   = blockIdx.x >> 4;             // j-slice 0..15
    const int gb  = g * GBAT;
    const int r_  = tid & 63;                    // row within slice
    const int ks  = tid >> 6;                    // k-slice 0..3 (= wave)
    const int jg  = q * RJ + r_;

    // ---- W -> registers: W[jg][ks*256 .. +255] = 64 f32x4 (one-time)
    f32x4 wreg[64];
    {
        const f32x4* wrow = (const f32x4*)(Whh + (size_t)jg * HH) + ks * 64;
#pragma unroll
        for (int i = 0; i < 64; ++i) wreg[i] = wrow[i];
    }

    const float bias_j = bias_ih[jg] + bias_bh[jg];
    const f32x4 wo     = ((const f32x4*)w_out)[tid];
    const float bout   = b_out[0];

    // ---- ring init: all 6 layers of h0 for this group's 4 batches (local)
#pragma unroll
    for (int l = 0; l < LL; ++l)
#pragma unroll
        for (int b = 0; b < GBAT; ++b)
            ring[l][b][tid] = *(const f32x4*)(h0 +
                ((size_t)l * BB + gb + b) * HH + (tid << 2));

    // ---- publish h0 layer-5 (parity 1, tag +64): the (0,0) P-gather source
    {
        int bb = tid >> 6, j = q * RJ + (tid & 63);
        astore1(&hstate[(((size_t)1 * BB + gb + bb) * LL + 5) * HH + j],
                h0[((size_t)5 * BB + gb + bb) * HH + j] + 64.0f);
    }

    for (int t = 0; t < TT; ++t) {
        const int   pw   = t & 1, pr = pw ^ 1;
        const float tagW = 8.0f + 8.0f * (float)((t >> 1) & 1);       // o(t)
        const float tagO = 8.0f + 8.0f * (float)(((t - 1) >> 1) & 1); // o(t-1)

#pragma unroll
        for (int l = 0; l < LL; ++l) {
            const int   lp   = l ? (l - 1) : (LL - 1);
            const int   pp   = l ? pw : pr;
            const float tagP = l ? tagW : ((t == 0) ? 64.0f : tagO);
            const float tolP = (l == 0 && t == 0) ? 16.0f : 1.0f;

            // ---- the ONLY cross-block gather: prev vector (16 KB/block)
            const float* baseP = hstate +
                (((size_t)pp * BB + gb) * LL + lp) * HH + (tid << 2);
            f32x4 P[GBAT];
            gather4(baseP, P);
            for (int it = 0; !valid4(P, tagP, tolP) && it < MAXIT; ++it) {
                __builtin_amdgcn_s_sleep(1);
                gather4(baseP, P);
            }

            // ---- detag; stage s = P + ring[l]; ring[lp] <- P (h_old of next step)
            f32x4 praw[GBAT];
#pragma unroll
            for (int b = 0; b < GBAT; ++b) {
                f32x4 p_ = (f32x4){P[b].x - tagP, P[b].y - tagP,
                                   P[b].z - tagP, P[b].w - tagP};
                praw[b] = p_;
                f32x4 h = ring[l][b][tid];          // same-tid slot: hazard-free
                s4[b][tid] = p_ + h;
                ring[lp][b][tid] = p_;
            }

            // ---- output projection for (t-1): P at l==0 IS y(t-1, 5)
            if (l == 0 && t > 0 && q < GBAT) {
                float val = praw[q].x * wo.x + praw[q].y * wo.y
                          + praw[q].z * wo.z + praw[q].w * wo.w;
#pragma unroll
                for (int off = 32; off; off >>= 1) val += __shfl_down(val, off, 64);
                if ((tid & 63) == 0) outred[ks] = val;
            }
            __syncthreads();   // s4 (and outred) ready

            if (l == 0 && t > 0 && q < GBAT && tid == 0)
                d_out[(size_t)(gb + q) * TT + (t - 1)] =
                    outred[0] + outred[1] + outred[2] + outred[3] + bout;

            // ---- 1024 reg-reg FMA: 4 batches x 64 f32x4, k-slice [ks*256,+256)
            float acc[GBAT];
#pragma unroll
            for (int b = 0; b < GBAT; ++b) acc[b] = 0.f;
            const f32x4* xb = &s4[0][ks * 64];
#pragma unroll
            for (int b = 0; b < GBAT; ++b) {
#pragma unroll
                for (int k4 = 0; k4 < 64; ++k4) {
                    f32x4 x = xb[b * 256 + k4];     // wave-uniform broadcast read
                    f32x4 w = wreg[k4];
                    acc[b] = fmaf(w.x, x.x, fmaf(w.y, x.y,
                             fmaf(w.z, x.z, fmaf(w.w, x.w, acc[b]))));
                }
            }
#pragma unroll
            for (int b = 0; b < GBAT; ++b) pred[ks][r_][b] = acc[b];
            __syncthreads();   // pred ready (also guards s4/ring reuse next cell)

            const int bb = tid >> 6;   // thread (r_, bb) owns output (row, batch)
            float ysum = pred[0][r_][bb] + pred[1][r_][bb]
                       + pred[2][r_][bb] + pred[3][r_][bb];
            float y = tanhf(ysum + bias_j);
            astore1(&hstate[(((size_t)pw * BB + gb + bb) * LL + l) * HH + jg],
                    y + tagW);         // tagged publish: the store IS the flag

            if (t == TT - 1)
                d_out[(size_t)BB * TT + ((size_t)l * BB + gb + bb) * HH + jg] = y;
        }
    }

    // ---- epilogue: out[b, 255] from y(255, 5) (parity 1, tag o(255)=16)
    if (q < GBAT) {
        const float* P = hstate +
            (((size_t)1 * BB + gb + q) * LL + 5) * HH + (tid << 2);
        f32x4 a;
        for (int it = 0; it < MAXIT; ++it) {
            float2 a0 = aload2(P), a1 = aload2(P + 2);
            a = (f32x4){a0.x, a0.y, a1.x, a1.y};
            if (fabsf(a.x - 16.0f) <= 1.0f && fabsf(a.y - 16.0f) <= 1.0f &&
                fabsf(a.z - 16.0f) <= 1.0f && fabsf(a.w - 16.0f) <= 1.0f) break;
            __builtin_amdgcn_s_sleep(1);
        }
        float val = (a.x - 16.0f) * wo.x + (a.y - 16.0f) * wo.y
                  + (a.z - 16.0f) * wo.z + (a.w - 16.0f) * wo.w;
#pragma unroll
        for (int off = 32; off; off >>= 1) val += __shfl_down(val, off, 64);
        if ((tid & 63) == 0) outred[ks] = val;
        __syncthreads();
        if (tid == 0)
            d_out[(size_t)(gb + q) * TT + (TT - 1)] =
                outred[0] + outred[1] + outred[2] + outred[3] + bout;
    }
}

extern "C" void kernel_launch(void* const* d_in, const int* in_sizes, int n_in,
                              void* d_out, int out_size, void* d_ws, size_t ws_size,
                              hipStream_t stream) {
    // inputs: 0:x(unused) 1:h0 2:weight_ih(unused) 3:bias_ih 4:weight_hh 5:bias_bh 6:w_out 7:b_out
    const float* h0      = (const float*)d_in[1];
    const float* bias_ih = (const float*)d_in[3];
    const float* Whh     = (const float*)d_in[4];
    const float* bias_bh = (const float*)d_in[5];
    const float* w_out   = (const float*)d_in[6];
    const float* b_out   = (const float*)d_in[7];

    float* hstate = (float*)d_ws;

    // scrub tags every launch: stale cross-launch tags would alias (ABA)
    hipMemsetAsync(hstate, 0, HSTATE_BYTES, stream);
    rnn_kernel<<<NGRP * NQJ, NTH, 0, stream>>>(h0, Whh, bias_ih, bias_bh,
                                               w_out, b_out, hstate,
                                               (float*)d_out);
}

// Round 13
// 88222.375 us; speedup vs baseline: 1.0186x; 1.0186x over previous
//
#include <hip/hip_runtime.h>

// B=64, T=256, H=1024, L=6. Cell: h = tanh((prev + h_old) @ W^T + b1 + b2).
// v13 = v12 (16 groups x 4 batches x 16 j-blocks, W in 256 VGPRs, LDS h_old
// ring, data-as-flag tags) + NARROW POLL. r12 diagnosis: the MALL agent-
// atomic path saturates at ~1.35 TB/s; v12's poll loop re-gathered 16KB/block
// per spin -> 102.7 GB FETCH, congestion spiral, 90ms. v8 itself was purely
// BW-bound (16 MB/cell-gen / 1.35 TB/s = 11.9us/cell). Fix: poll just 64
// words (one per producer-block x batch, one wave) until tagged, THEN gather
// the 16KB once, validate, bad-mask re-poll only stragglers (v8-style, rare).
// Useful traffic: 4 MB/cell-gen; poll overhead ~60x smaller than v12.
// Tags: y stored as y+o(t), o(t)=8+8*((t>>1)&1); h0 layer-5 published +64.
// Bounded spins -> failures visible. hstate scrubbed per launch (tag ABA).

#define BB 64
#define TT 256
#define HH 1024
#define LL 6
#define NGRP 16   // groups (4 batches each)
#define GBAT 4    // batches per group
#define NQJ 16    // j-slice blocks per group
#define RJ 64     // j rows per block
#define NTH 256
#define MAXPOLL (1 << 18)
#define MAXFIX  (1 << 14)

#define HSTATE_BYTES (2ull * BB * LL * HH * 4)   // [parity][b][l][k], 3 MB

typedef float f32x4 __attribute__((ext_vector_type(4)));

static __device__ __forceinline__ float2 aload2(const float* p) {
    unsigned long long u = __hip_atomic_load((const unsigned long long*)p,
        __ATOMIC_RELAXED, __HIP_MEMORY_SCOPE_AGENT);
    union { unsigned long long u; float2 f; } c; c.u = u; return c.f;
}
static __device__ __forceinline__ float aload1(const float* p) {
    return __hip_atomic_load(p, __ATOMIC_RELAXED, __HIP_MEMORY_SCOPE_AGENT);
}
static __device__ __forceinline__ void astore1(float* p, float v) {
    __hip_atomic_store(p, v, __ATOMIC_RELAXED, __HIP_MEMORY_SCOPE_AGENT);
}

__global__ void __launch_bounds__(NTH, 1)
rnn_kernel(const float* __restrict__ h0,
           const float* __restrict__ Whh,
           const float* __restrict__ bias_ih,
           const float* __restrict__ bias_bh,
           const float* __restrict__ w_out,
           const float* __restrict__ b_out,
           float* hstate,
           float* __restrict__ d_out)
{
    __shared__ f32x4 ring[LL][GBAT][256];    // 96 KB: h_old cache, per-thread slots
    __shared__ f32x4 s4[GBAT][256];          // 16 KB: s = prev + h_old
    __shared__ float pred[4][RJ][GBAT + 1];  //  5 KB: per-kslice partials
    __shared__ float outred[4];

    const int tid = threadIdx.x;
    const int g   = blockIdx.x & (NGRP - 1);     // group (4 batches)
    const int q   = blockIdx.x >> 4;             // j-slice 0..15
    const int gb  = g * GBAT;
    const int r_  = tid & 63;                    // row within slice
    const int ks  = tid >> 6;                    // k-slice 0..3 (= wave)
    const int jg  = q * RJ + r_;

    // ---- W -> registers: W[jg][ks*256 .. +255] = 64 f32x4 (one-time)
    f32x4 wreg[64];
    {
        const f32x4* wrow = (const f32x4*)(Whh + (size_t)jg * HH) + ks * 64;
#pragma unroll
        for (int i = 0; i < 64; ++i) wreg[i] = wrow[i];
    }

    const float bias_j = bias_ih[jg] + bias_bh[jg];
    const f32x4 wo     = ((const f32x4*)w_out)[tid];
    const float bout   = b_out[0];

    // ---- ring init: all 6 layers of h0 for this group's 4 batches (local)
#pragma unroll
    for (int l = 0; l < LL; ++l)
#pragma unroll
        for (int b = 0; b < GBAT; ++b)
            ring[l][b][tid] = *(const f32x4*)(h0 +
                ((size_t)l * BB + gb + b) * HH + (tid << 2));

    // ---- publish h0 layer-5 (parity 1, tag +64): the (0,0) P-gather source
    {
        int bb = tid >> 6, j = q * RJ + (tid & 63);
        astore1(&hstate[(((size_t)1 * BB + gb + bb) * LL + 5) * HH + j],
                h0[((size_t)5 * BB + gb + bb) * HH + j] + 64.0f);
    }

    for (int t = 0; t < TT; ++t) {
        const int   pw   = t & 1, pr = pw ^ 1;
        const float tagW = 8.0f + 8.0f * (float)((t >> 1) & 1);       // o(t)
        const float tagO = 8.0f + 8.0f * (float)(((t - 1) >> 1) & 1); // o(t-1)

#pragma unroll
        for (int l = 0; l < LL; ++l) {
            const int   lp   = l ? (l - 1) : (LL - 1);
            const int   pp   = l ? pw : pr;
            const float tagP = l ? tagW : ((t == 0) ? 64.0f : tagO);
            const float tolP = (l == 0 && t == 0) ? 16.0f : 1.0f;

            const float* vecbase = hstate + (((size_t)pp * BB + gb) * LL + lp) * HH;

            // ---- NARROW POLL: wave 0, lane = bb*16 + qp -> word qp*64 of batch bb
            if (tid < 64) {
                const int bb = tid >> 4, qp = tid & 15;
                const float* pw_ = vecbase + (size_t)bb * (LL * HH) + qp * RJ;
                bool okl = false;
                for (int it = 0; it < MAXPOLL; ++it) {
                    float v = aload1(pw_);
                    if (fabsf(v - tagP) <= tolP) { okl = true; break; }
                    __builtin_amdgcn_s_sleep(2);
                }
                (void)okl;   // timeout -> proceed; full validate below catches it
            }
            __syncthreads();   // whole block waits for detection

            // ---- ONE wide gather (16 KB), then validate + bad-mask fix-up
            const float* baseP = vecbase + (tid << 2);
            f32x4 P[GBAT];
#pragma unroll
            for (int b = 0; b < GBAT; ++b) {
                const float* p = baseP + (size_t)b * (LL * HH);
                float2 a = aload2(p), c = aload2(p + 2);
                P[b] = (f32x4){a.x, a.y, c.x, c.y};
            }
            unsigned bad = 0;
#pragma unroll
            for (int b = 0; b < GBAT; ++b) {
                if (fabsf(P[b].x - tagP) > tolP || fabsf(P[b].y - tagP) > tolP) bad |= 1u << (2 * b);
                if (fabsf(P[b].z - tagP) > tolP || fabsf(P[b].w - tagP) > tolP) bad |= 2u << (2 * b);
            }
            for (int it = 0; bad && it < MAXFIX; ++it) {   // stragglers only (rare)
                __builtin_amdgcn_s_sleep(1);
#pragma unroll
                for (int b = 0; b < GBAT; ++b) {
                    const float* p = baseP + (size_t)b * (LL * HH);
                    if (bad & (1u << (2 * b))) {
                        float2 a = aload2(p);
                        if (fabsf(a.x - tagP) <= tolP && fabsf(a.y - tagP) <= tolP) {
                            P[b].x = a.x; P[b].y = a.y; bad &= ~(1u << (2 * b));
                        }
                    }
                    if (bad & (2u << (2 * b))) {
                        float2 c = aload2(p + 2);
                        if (fabsf(c.x - tagP) <= tolP && fabsf(c.y - tagP) <= tolP) {
                            P[b].z = c.x; P[b].w = c.y; bad &= ~(2u << (2 * b));
                        }
                    }
                }
            }

            // ---- detag; stage s = P + ring[l]; ring[lp] <- P (h_old of next step)
            f32x4 praw[GBAT];
#pragma unroll
            for (int b = 0; b < GBAT; ++b) {
                f32x4 p_ = (f32x4){P[b].x - tagP, P[b].y - tagP,
                                   P[b].z - tagP, P[b].w - tagP};
                praw[b] = p_;
                f32x4 h = ring[l][b][tid];          // same-tid slot: hazard-free
                s4[b][tid] = p_ + h;
                ring[lp][b][tid] = p_;
            }

            // ---- output projection for (t-1): P at l==0 IS y(t-1, 5)
            if (l == 0 && t > 0 && q < GBAT) {
                float val = praw[q].x * wo.x + praw[q].y * wo.y
                          + praw[q].z * wo.z + praw[q].w * wo.w;
#pragma unroll
                for (int off = 32; off; off >>= 1) val += __shfl_down(val, off, 64);
                if ((tid & 63) == 0) outred[ks] = val;
            }
            __syncthreads();   // s4 (and outred) ready

            if (l == 0 && t > 0 && q < GBAT && tid == 0)
                d_out[(size_t)(gb + q) * TT + (t - 1)] =
                    outred[0] + outred[1] + outred[2] + outred[3] + bout;

            // ---- 1024 reg-reg FMA: 4 batches x 64 f32x4, k-slice [ks*256,+256)
            float acc[GBAT];
#pragma unroll
            for (int b = 0; b < GBAT; ++b) acc[b] = 0.f;
            const f32x4* xb = &s4[0][ks * 64];
#pragma unroll
            for (int b = 0; b < GBAT; ++b) {
#pragma unroll
                for (int k4 = 0; k4 < 64; ++k4) {
                    f32x4 x = xb[b * 256 + k4];     // wave-uniform broadcast read
                    f32x4 w = wreg[k4];
                    acc[b] = fmaf(w.x, x.x, fmaf(w.y, x.y,
                             fmaf(w.z, x.z, fmaf(w.w, x.w, acc[b]))));
                }
            }
#pragma unroll
            for (int b = 0; b < GBAT; ++b) pred[ks][r_][b] = acc[b];
            __syncthreads();   // pred ready (also guards s4/ring reuse next cell)

            const int bb = tid >> 6;   // thread (r_, bb) owns output (row, batch)
            float ysum = pred[0][r_][bb] + pred[1][r_][bb]
                       + pred[2][r_][bb] + pred[3][r_][bb];
            float y = tanhf(ysum + bias_j);
            astore1(&hstate[(((size_t)pw * BB + gb + bb) * LL + l) * HH + jg],
                    y + tagW);         // tagged publish: the store IS the flag

            if (t == TT - 1)
                d_out[(size_t)BB * TT + ((size_t)l * BB + gb + bb) * HH + jg] = y;
        }
    }

    // ---- epilogue: out[b, 255] from y(255, 5) (parity 1, tag o(255)=16)
    if (q < GBAT) {
        const float* P = hstate +
            (((size_t)1 * BB + gb + q) * LL + 5) * HH + (tid << 2);
        f32x4 a;
        for (int it = 0; it < MAXFIX; ++it) {
            float2 a0 = aload2(P), a1 = aload2(P + 2);
            a = (f32x4){a0.x, a0.y, a1.x, a1.y};
            if (fabsf(a.x - 16.0f) <= 1.0f && fabsf(a.y - 16.0f) <= 1.0f &&
                fabsf(a.z - 16.0f) <= 1.0f && fabsf(a.w - 16.0f) <= 1.0f) break;
            __builtin_amdgcn_s_sleep(1);
        }
        float val = (a.x - 16.0f) * wo.x + (a.y - 16.0f) * wo.y
                  + (a.z - 16.0f) * wo.z + (a.w - 16.0f) * wo.w;
#pragma unroll
        for (int off = 32; off; off >>= 1) val += __shfl_down(val, off, 64);
        if ((tid & 63) == 0) outred[ks] = val;
        __syncthreads();
        if (tid == 0)
            d_out[(size_t)(gb + q) * TT + (TT - 1)] =
                outred[0] + outred[1] + outred[2] + outred[3] + bout;
    }
}

extern "C" void kernel_launch(void* const* d_in, const int* in_sizes, int n_in,
                              void* d_out, int out_size, void* d_ws, size_t ws_size,
                              hipStream_t stream) {
    // inputs: 0:x(unused) 1:h0 2:weight_ih(unused) 3:bias_ih 4:weight_hh 5:bias_bh 6:w_out 7:b_out
    const float* h0      = (const float*)d_in[1];
    const float* bias_ih = (const float*)d_in[3];
    const float* Whh     = (const float*)d_in[4];
    const float* bias_bh = (const float*)d_in[5];
    const float* w_out   = (const float*)d_in[6];
    const float* b_out   = (const float*)d_in[7];

    float* hstate = (float*)d_ws;

    // scrub tags every launch: stale cross-launch tags would alias (ABA)
    hipMemsetAsync(hstate, 0, HSTATE_BYTES, stream);
    rnn_kernel<<<NGRP * NQJ, NTH, 0, stream>>>(h0, Whh, bias_ih, bias_bh,
                                               w_out, b_out, hstate,
                                               (float*)d_out);
}